// Round 1
// baseline (446.650 us; speedup 1.0000x reference)
//
#include <hip/hip_runtime.h>
#include <stdint.h>
#include <math.h>

#define NBATCH 16384
#define NW16   (NBATCH * 16)   // uint64 spike-mask words per t-plane (1024 bits/row = 16 words)

// =====================================================================
// Kernel 1: c = [obs|ctx] @ W1^T + b1  (K=192), then 4-step LIF with
// constant input c, emit bit-packed spikes s1[t][b][w] (w: 16 u64/row).
// 128x128 tile, 8x8 microtile, BK=32, k-major LDS, float4 fragments.
// =====================================================================
struct GemmSm { float Xs[32][132]; float Ws[32][132]; };
union __align__(16) K1Sm { GemmSm g; unsigned char pk[4][128][16]; };

__global__ __launch_bounds__(256) void k1_gemm_lif(
    const float* __restrict__ obs, const float* __restrict__ ctx,
    const float* __restrict__ W1,  const float* __restrict__ b1,
    unsigned long long* __restrict__ s1)
{
  __shared__ K1Sm sm;
  const int tid = threadIdx.x;
  const int tx = tid & 15, ty = tid >> 4;
  const int m0 = blockIdx.y * 128;   // batch rows
  const int n0 = blockIdx.x * 128;   // hidden cols
  const int c4 = tid & 7;            // which float4 along k (0..7 -> k=4*c4)
  const int rb = tid >> 3;           // 0..31

  float acc[8][8];
  #pragma unroll
  for (int i = 0; i < 8; ++i)
    #pragma unroll
    for (int j = 0; j < 8; ++j) acc[i][j] = 0.f;

  for (int kc = 0; kc < 6; ++kc) {
    const int k0 = kc * 32;
    if (kc) __syncthreads();
    // ---- stage X (concat obs|ctx) and W1, transposed to k-major ----
    #pragma unroll
    for (int q = 0; q < 4; ++q) {
      const int r = rb + 32 * q;
      float4 xv;
      if (k0 < 128) xv = *(const float4*)(obs + (size_t)(m0 + r) * 128 + k0 + 4 * c4);
      else          xv = *(const float4*)(ctx + (size_t)(m0 + r) * 64 + (k0 - 128) + 4 * c4);
      const int kl = 4 * c4;
      sm.g.Xs[kl + 0][r] = xv.x; sm.g.Xs[kl + 1][r] = xv.y;
      sm.g.Xs[kl + 2][r] = xv.z; sm.g.Xs[kl + 3][r] = xv.w;
      float4 wv = *(const float4*)(W1 + (size_t)(n0 + r) * 192 + k0 + 4 * c4);
      sm.g.Ws[kl + 0][r] = wv.x; sm.g.Ws[kl + 1][r] = wv.y;
      sm.g.Ws[kl + 2][r] = wv.z; sm.g.Ws[kl + 3][r] = wv.w;
    }
    __syncthreads();
    // ---- 8x8 microtile FMA ----
    #pragma unroll
    for (int kk = 0; kk < 32; ++kk) {
      const float4* xr = (const float4*)sm.g.Xs[kk];
      const float4* wr = (const float4*)sm.g.Ws[kk];
      float4 a0 = xr[ty * 2], a1 = xr[ty * 2 + 1];
      float4 b0 = wr[tx * 2], b1v4 = wr[tx * 2 + 1];
      float av[8] = {a0.x, a0.y, a0.z, a0.w, a1.x, a1.y, a1.z, a1.w};
      float bv[8] = {b0.x, b0.y, b0.z, b0.w, b1v4.x, b1v4.y, b1v4.z, b1v4.w};
      #pragma unroll
      for (int i = 0; i < 8; ++i)
        #pragma unroll
        for (int j = 0; j < 8; ++j) acc[i][j] += av[i] * bv[j];
    }
  }

  // bias
  float4 bA = *(const float4*)(b1 + n0 + tx * 8);
  float4 bB = *(const float4*)(b1 + n0 + tx * 8 + 4);
  float bvv[8] = {bA.x, bA.y, bA.z, bA.w, bB.x, bB.y, bB.z, bB.w};

  // ---- LIF (input constant across t): v = v + (c - v)*0.5; spike v>=1; hard reset ----
  unsigned int byt[4][8];
  #pragma unroll
  for (int t = 0; t < 4; ++t)
    #pragma unroll
    for (int i = 0; i < 8; ++i) byt[t][i] = 0u;

  #pragma unroll
  for (int i = 0; i < 8; ++i) {
    #pragma unroll
    for (int j = 0; j < 8; ++j) {
      const float c = acc[i][j] + bvv[j];
      float v = 0.f;
      #pragma unroll
      for (int t = 0; t < 4; ++t) {
        v = v + (c - v) * 0.5f;
        if (v >= 1.0f) { byt[t][i] |= (1u << j); v = 0.f; }
      }
    }
  }

  __syncthreads();  // everyone done reading Xs/Ws before aliasing as pk
  #pragma unroll
  for (int t = 0; t < 4; ++t)
    #pragma unroll
    for (int i = 0; i < 8; ++i)
      sm.pk[t][ty * 8 + i][tx] = (unsigned char)byt[t][i];
  __syncthreads();

  // assemble 64-bit words and store: s1[t][b][wword]
  const int t = tid >> 6, r0 = tid & 63;
  #pragma unroll
  for (int h = 0; h < 2; ++h) {
    const int rr = r0 + 64 * h;
    #pragma unroll
    for (int w = 0; w < 2; ++w) {
      unsigned long long word = *(const unsigned long long*)&sm.pk[t][rr][w * 8];
      s1[(size_t)t * NW16 + (size_t)(m0 + rr) * 16 + (n0 >> 6) + w] = word;
    }
  }
}

// =====================================================================
// Kernel 2: layer-2 LIF over 4 timesteps. A-matrix is binary spikes s1.
// Wave-per-batch-row; row-empty fast path (c = b2[o]); honest sparse
// fallback dot over W2 if any spike bit is set.
// =====================================================================
__global__ __launch_bounds__(256) void k2_lif(
    const unsigned long long* __restrict__ s1, const float* __restrict__ W2,
    const float* __restrict__ b2, unsigned long long* __restrict__ s2)
{
  __shared__ unsigned long long M[4][4][16];
  __shared__ unsigned long long F[4][4];
  const int tid = threadIdx.x;
  const int wv = tid >> 6, lane = tid & 63;
  const int b = blockIdx.x * 4 + wv;

  M[wv][lane >> 4][lane & 15] =
      s1[(size_t)(lane >> 4) * NW16 + (size_t)b * 16 + (lane & 15)];
  __syncthreads();
  if (lane < 4) {
    unsigned long long f = 0;
    #pragma unroll
    for (int w = 0; w < 16; ++w) f |= M[wv][lane][w];
    F[wv][lane] = f;
  }
  __syncthreads();

  unsigned long long myword = 0;
  for (int j = 0; j < 16; ++j) {
    const int o = j * 64 + lane;
    const float cb = b2[o];
    float v = 0.f;
    bool sb[4];
    #pragma unroll
    for (int tt = 0; tt < 4; ++tt) {
      float c = cb;
      if (F[wv][tt]) {  // wave-uniform
        for (int wl = 0; wl < 16; ++wl) {
          unsigned long long m = M[wv][tt][wl];
          while (m) {
            const int k = wl * 64 + __builtin_ctzll(m);
            c += W2[(size_t)o * 1024 + k];
            m &= (m - 1);
          }
        }
      }
      v = v + (c - v) * 0.5f;
      const bool s = (v >= 1.0f);
      sb[tt] = s;
      if (s) v = 0.f;
    }
    #pragma unroll
    for (int tt = 0; tt < 4; ++tt) {
      unsigned long long w = __ballot(sb[tt]);
      if (lane == j * 4 + tt) myword = w;
    }
  }
  const int tt = lane & 3, jj = lane >> 2;
  s2[(size_t)tt * NW16 + (size_t)b * 16 + jj] = myword;
}

// =====================================================================
// Kernel 3: layer-3 LIF (same sparse scheme) + mean over t -> feat in
// LDS, then fused final GEMM [1024->32] + tanh + clipped noise.
// =====================================================================
__global__ __launch_bounds__(256) void k3_lif_out(
    const unsigned long long* __restrict__ s2, const float* __restrict__ W3,
    const float* __restrict__ b3, const float* __restrict__ Wm,
    const float* __restrict__ bm, const float* __restrict__ noise,
    float* __restrict__ out)
{
  __shared__ unsigned long long M[4][4][16];
  __shared__ unsigned long long F[4][4];
  __shared__ float featL[4][1024];
  const int tid = threadIdx.x;
  const int wv = tid >> 6, lane = tid & 63;
  const int b = blockIdx.x * 4 + wv;

  M[wv][lane >> 4][lane & 15] =
      s2[(size_t)(lane >> 4) * NW16 + (size_t)b * 16 + (lane & 15)];
  __syncthreads();
  if (lane < 4) {
    unsigned long long f = 0;
    #pragma unroll
    for (int w = 0; w < 16; ++w) f |= M[wv][lane][w];
    F[wv][lane] = f;
  }
  __syncthreads();

  for (int j = 0; j < 16; ++j) {
    const int o = j * 64 + lane;
    const float cb = b3[o];
    float v = 0.f, fs = 0.f;
    #pragma unroll
    for (int tt = 0; tt < 4; ++tt) {
      float c = cb;
      if (F[wv][tt]) {
        for (int wl = 0; wl < 16; ++wl) {
          unsigned long long m = M[wv][tt][wl];
          while (m) {
            const int k = wl * 64 + __builtin_ctzll(m);
            c += W3[(size_t)o * 1024 + k];
            m &= (m - 1);
          }
        }
      }
      v = v + (c - v) * 0.5f;
      if (v >= 1.0f) { fs += 1.0f; v = 0.f; }
    }
    featL[wv][o] = fs * 0.25f;  // mean over T=4
  }
  __syncthreads();

  // final: action_mean = tanh(feat @ Wm^T + bm); action = + clip(noise)
  if (tid < 128) {
    const int bl = tid >> 5, a = tid & 31;
    const int bg = blockIdx.x * 4 + bl;
    const float4* fr = (const float4*)featL[bl];
    const float4* wr = (const float4*)(Wm + (size_t)a * 1024);
    float acc = 0.f;
    #pragma unroll 4
    for (int k4 = 0; k4 < 256; ++k4) {
      float4 f = fr[k4];
      float4 w = wr[k4];
      acc += f.x * w.x + f.y * w.y + f.z * w.z + f.w * w.w;
    }
    const float z = acc + bm[a];
    const float am = tanhf(z);
    float nz = noise[a];
    nz = fminf(fmaxf(nz, -0.1f), 0.1f);
    out[(size_t)bg * 32 + a] = am;
    out[(size_t)NBATCH * 32 + (size_t)bg * 32 + a] = am + nz;
  }
}

// =====================================================================
extern "C" void kernel_launch(void* const* d_in, const int* in_sizes, int n_in,
                              void* d_out, int out_size, void* d_ws, size_t ws_size,
                              hipStream_t stream) {
  const float* obs   = (const float*)d_in[0];
  const float* ctx   = (const float*)d_in[1];
  const float* noise = (const float*)d_in[2];
  const float* W1    = (const float*)d_in[3];
  const float* b1    = (const float*)d_in[4];
  const float* W2    = (const float*)d_in[5];
  const float* b2    = (const float*)d_in[6];
  const float* W3    = (const float*)d_in[7];
  const float* b3    = (const float*)d_in[8];
  const float* Wm    = (const float*)d_in[9];
  const float* bm    = (const float*)d_in[10];
  float* out = (float*)d_out;

  unsigned long long* s1 = (unsigned long long*)d_ws;          // 4*NW16 u64 = 8 MB
  unsigned long long* s2 = s1 + (size_t)4 * NW16;              // 8 MB more

  dim3 g1(1024 / 128, NBATCH / 128);  // (8, 128)
  k1_gemm_lif<<<g1, 256, 0, stream>>>(obs, ctx, W1, b1, s1);
  k2_lif<<<NBATCH / 4, 256, 0, stream>>>(s1, W2, b2, s2);
  k3_lif_out<<<NBATCH / 4, 256, 0, stream>>>(s2, W3, b3, Wm, bm, noise, out);
}

// Round 2
// 228.402 us; speedup vs baseline: 1.9555x; 1.9555x over previous
//
#include <hip/hip_runtime.h>
#include <stdint.h>
#include <math.h>

#define NBATCH 16384
#define NW16   (NBATCH * 16)   // uint64 spike-mask words per t-plane (1024 bits/row = 16 words)

// =====================================================================
// Kernel 1: c = [obs|ctx] @ W1^T + b1  (K=192), then 4-step LIF with
// constant input c, emit bit-packed spikes s1[t][b][w] (w: 16 u64/row).
// 128x128 tile, 8x8 microtile, BK=32, k-major LDS, float4 fragments.
// =====================================================================
struct GemmSm { float Xs[32][132]; float Ws[32][132]; };
union __align__(16) K1Sm { GemmSm g; unsigned char pk[4][128][16]; };

__global__ __launch_bounds__(256) void k1_gemm_lif(
    const float* __restrict__ obs, const float* __restrict__ ctx,
    const float* __restrict__ W1,  const float* __restrict__ b1,
    unsigned long long* __restrict__ s1)
{
  __shared__ K1Sm sm;
  const int tid = threadIdx.x;
  const int tx = tid & 15, ty = tid >> 4;
  const int m0 = blockIdx.y * 128;   // batch rows
  const int n0 = blockIdx.x * 128;   // hidden cols
  const int c4 = tid & 7;            // which float4 along k (0..7 -> k=4*c4)
  const int rb = tid >> 3;           // 0..31

  float acc[8][8];
  #pragma unroll
  for (int i = 0; i < 8; ++i)
    #pragma unroll
    for (int j = 0; j < 8; ++j) acc[i][j] = 0.f;

  for (int kc = 0; kc < 6; ++kc) {
    const int k0 = kc * 32;
    if (kc) __syncthreads();
    // ---- stage X (concat obs|ctx) and W1, transposed to k-major ----
    #pragma unroll
    for (int q = 0; q < 4; ++q) {
      const int r = rb + 32 * q;
      float4 xv;
      if (k0 < 128) xv = *(const float4*)(obs + (size_t)(m0 + r) * 128 + k0 + 4 * c4);
      else          xv = *(const float4*)(ctx + (size_t)(m0 + r) * 64 + (k0 - 128) + 4 * c4);
      const int kl = 4 * c4;
      sm.g.Xs[kl + 0][r] = xv.x; sm.g.Xs[kl + 1][r] = xv.y;
      sm.g.Xs[kl + 2][r] = xv.z; sm.g.Xs[kl + 3][r] = xv.w;
      float4 wv = *(const float4*)(W1 + (size_t)(n0 + r) * 192 + k0 + 4 * c4);
      sm.g.Ws[kl + 0][r] = wv.x; sm.g.Ws[kl + 1][r] = wv.y;
      sm.g.Ws[kl + 2][r] = wv.z; sm.g.Ws[kl + 3][r] = wv.w;
    }
    __syncthreads();
    // ---- 8x8 microtile FMA ----
    #pragma unroll
    for (int kk = 0; kk < 32; ++kk) {
      const float4* xr = (const float4*)sm.g.Xs[kk];
      const float4* wr = (const float4*)sm.g.Ws[kk];
      float4 a0 = xr[ty * 2], a1 = xr[ty * 2 + 1];
      float4 b0 = wr[tx * 2], b1v4 = wr[tx * 2 + 1];
      float av[8] = {a0.x, a0.y, a0.z, a0.w, a1.x, a1.y, a1.z, a1.w};
      float bv[8] = {b0.x, b0.y, b0.z, b0.w, b1v4.x, b1v4.y, b1v4.z, b1v4.w};
      #pragma unroll
      for (int i = 0; i < 8; ++i)
        #pragma unroll
        for (int j = 0; j < 8; ++j) acc[i][j] += av[i] * bv[j];
    }
  }

  // bias
  float4 bA = *(const float4*)(b1 + n0 + tx * 8);
  float4 bB = *(const float4*)(b1 + n0 + tx * 8 + 4);
  float bvv[8] = {bA.x, bA.y, bA.z, bA.w, bB.x, bB.y, bB.z, bB.w};

  // ---- LIF (input constant across t): v = v + (c - v)*0.5; spike v>=1; hard reset ----
  unsigned int byt[4][8];
  #pragma unroll
  for (int t = 0; t < 4; ++t)
    #pragma unroll
    for (int i = 0; i < 8; ++i) byt[t][i] = 0u;

  #pragma unroll
  for (int i = 0; i < 8; ++i) {
    #pragma unroll
    for (int j = 0; j < 8; ++j) {
      const float c = acc[i][j] + bvv[j];
      float v = 0.f;
      #pragma unroll
      for (int t = 0; t < 4; ++t) {
        v = v + (c - v) * 0.5f;
        if (v >= 1.0f) { byt[t][i] |= (1u << j); v = 0.f; }
      }
    }
  }

  __syncthreads();  // everyone done reading Xs/Ws before aliasing as pk
  #pragma unroll
  for (int t = 0; t < 4; ++t)
    #pragma unroll
    for (int i = 0; i < 8; ++i)
      sm.pk[t][ty * 8 + i][tx] = (unsigned char)byt[t][i];
  __syncthreads();

  // assemble 64-bit words and store: s1[t][b][wword]
  const int t = tid >> 6, r0 = tid & 63;
  #pragma unroll
  for (int h = 0; h < 2; ++h) {
    const int rr = r0 + 64 * h;
    #pragma unroll
    for (int w = 0; w < 2; ++w) {
      unsigned long long word = *(const unsigned long long*)&sm.pk[t][rr][w * 8];
      s1[(size_t)t * NW16 + (size_t)(m0 + rr) * 16 + (n0 >> 6) + w] = word;
    }
  }
}

// =====================================================================
// Kernel 2: layer-2 LIF over 4 timesteps. A-matrix is binary spikes s1.
// Wave-per-batch-row; row-empty fast path (c = b2[o]); honest sparse
// fallback dot over W2 if any spike bit is set.
// =====================================================================
__global__ __launch_bounds__(256) void k2_lif(
    const unsigned long long* __restrict__ s1, const float* __restrict__ W2,
    const float* __restrict__ b2, unsigned long long* __restrict__ s2)
{
  __shared__ unsigned long long M[4][4][16];
  __shared__ unsigned long long F[4][4];
  const int tid = threadIdx.x;
  const int wv = tid >> 6, lane = tid & 63;
  const int b = blockIdx.x * 4 + wv;

  M[wv][lane >> 4][lane & 15] =
      s1[(size_t)(lane >> 4) * NW16 + (size_t)b * 16 + (lane & 15)];
  __syncthreads();
  if (lane < 4) {
    unsigned long long f = 0;
    #pragma unroll
    for (int w = 0; w < 16; ++w) f |= M[wv][lane][w];
    F[wv][lane] = f;
  }
  __syncthreads();

  unsigned long long myword = 0;
  for (int j = 0; j < 16; ++j) {
    const int o = j * 64 + lane;
    const float cb = b2[o];
    float v = 0.f;
    bool sb[4];
    #pragma unroll
    for (int tt = 0; tt < 4; ++tt) {
      float c = cb;
      if (F[wv][tt]) {  // wave-uniform
        for (int wl = 0; wl < 16; ++wl) {
          unsigned long long m = M[wv][tt][wl];
          while (m) {
            const int k = wl * 64 + __builtin_ctzll(m);
            c += W2[(size_t)o * 1024 + k];
            m &= (m - 1);
          }
        }
      }
      v = v + (c - v) * 0.5f;
      const bool s = (v >= 1.0f);
      sb[tt] = s;
      if (s) v = 0.f;
    }
    #pragma unroll
    for (int tt = 0; tt < 4; ++tt) {
      unsigned long long w = __ballot(sb[tt]);
      if (lane == j * 4 + tt) myword = w;
    }
  }
  const int tt = lane & 3, jj = lane >> 2;
  s2[(size_t)tt * NW16 + (size_t)b * 16 + jj] = myword;
}

// =====================================================================
// Kernel 3: layer-3 LIF (same sparse scheme) + mean over t -> feat in
// LDS, then fused final GEMM [1024->32] + tanh + clipped noise.
// Final dot is SKIPPED (exactly 0) when the feat row is all-zero, with
// an honest dense fallback when any layer-3 spike fired.
// =====================================================================
__global__ __launch_bounds__(256) void k3_lif_out(
    const unsigned long long* __restrict__ s2, const float* __restrict__ W3,
    const float* __restrict__ b3, const float* __restrict__ Wm,
    const float* __restrict__ bm, const float* __restrict__ noise,
    float* __restrict__ out)
{
  __shared__ unsigned long long M[4][4][16];
  __shared__ unsigned long long F[4][4];
  __shared__ float featL[4][1024];
  __shared__ int featNZ[4];          // per-batch-row: any nonzero feat entry?
  const int tid = threadIdx.x;
  const int wv = tid >> 6, lane = tid & 63;
  const int b = blockIdx.x * 4 + wv;

  M[wv][lane >> 4][lane & 15] =
      s2[(size_t)(lane >> 4) * NW16 + (size_t)b * 16 + (lane & 15)];
  __syncthreads();
  if (lane < 4) {
    unsigned long long f = 0;
    #pragma unroll
    for (int w = 0; w < 16; ++w) f |= M[wv][lane][w];
    F[wv][lane] = f;
  }
  __syncthreads();

  bool anyNZ = false;
  for (int j = 0; j < 16; ++j) {
    const int o = j * 64 + lane;
    const float cb = b3[o];
    float v = 0.f, fs = 0.f;
    #pragma unroll
    for (int tt = 0; tt < 4; ++tt) {
      float c = cb;
      if (F[wv][tt]) {
        for (int wl = 0; wl < 16; ++wl) {
          unsigned long long m = M[wv][tt][wl];
          while (m) {
            const int k = wl * 64 + __builtin_ctzll(m);
            c += W3[(size_t)o * 1024 + k];
            m &= (m - 1);
          }
        }
      }
      v = v + (c - v) * 0.5f;
      if (v >= 1.0f) { fs += 1.0f; v = 0.f; }
    }
    anyNZ |= (fs > 0.f);
    featL[wv][o] = fs * 0.25f;  // mean over T=4
  }
  {
    unsigned long long rm = __ballot(anyNZ);
    if (lane == 0) featNZ[wv] = (rm != 0ull) ? 1 : 0;
  }
  __syncthreads();

  // final: action_mean = tanh(feat @ Wm^T + bm); action = + clip(noise)
  if (tid < 128) {
    const int bl = tid >> 5, a = tid & 31;
    const int bg = blockIdx.x * 4 + bl;
    float acc = 0.f;
    if (featNZ[bl]) {  // dot of an all-zero feat row is exactly 0 -> skip
      const float4* fr = (const float4*)featL[bl];
      const float4* wr = (const float4*)(Wm + (size_t)a * 1024);
      #pragma unroll 4
      for (int k4 = 0; k4 < 256; ++k4) {
        float4 f = fr[k4];
        float4 w = wr[k4];
        acc += f.x * w.x + f.y * w.y + f.z * w.z + f.w * w.w;
      }
    }
    const float z = acc + bm[a];
    const float am = tanhf(z);
    float nz = noise[a];
    nz = fminf(fmaxf(nz, -0.1f), 0.1f);
    out[(size_t)bg * 32 + a] = am;
    out[(size_t)NBATCH * 32 + (size_t)bg * 32 + a] = am + nz;
  }
}

// =====================================================================
extern "C" void kernel_launch(void* const* d_in, const int* in_sizes, int n_in,
                              void* d_out, int out_size, void* d_ws, size_t ws_size,
                              hipStream_t stream) {
  const float* obs   = (const float*)d_in[0];
  const float* ctx   = (const float*)d_in[1];
  const float* noise = (const float*)d_in[2];
  const float* W1    = (const float*)d_in[3];
  const float* b1    = (const float*)d_in[4];
  const float* W2    = (const float*)d_in[5];
  const float* b2    = (const float*)d_in[6];
  const float* W3    = (const float*)d_in[7];
  const float* b3    = (const float*)d_in[8];
  const float* Wm    = (const float*)d_in[9];
  const float* bm    = (const float*)d_in[10];
  float* out = (float*)d_out;

  unsigned long long* s1 = (unsigned long long*)d_ws;          // 4*NW16 u64 = 8 MB
  unsigned long long* s2 = s1 + (size_t)4 * NW16;              // 8 MB more

  dim3 g1(1024 / 128, NBATCH / 128);  // (8, 128)
  k1_gemm_lif<<<g1, 256, 0, stream>>>(obs, ctx, W1, b1, s1);
  k2_lif<<<NBATCH / 4, 256, 0, stream>>>(s1, W2, b2, s2);
  k3_lif_out<<<NBATCH / 4, 256, 0, stream>>>(s2, W3, b3, Wm, bm, noise, out);
}

// Round 3
// 103.677 us; speedup vs baseline: 4.3081x; 2.2030x over previous
//
#include <hip/hip_runtime.h>
#include <stdint.h>
#include <math.h>

#define NB 16384

// ws layout:
//   int   ws_i[0]      : fallback count (zeroed by hipMemsetAsync)
//   uint  ws_u[1]      : max row ||W1_o||^2  (atomic-max, float bits)
//   uint  ws_u[2]      : max |b1|            (atomic-max, float bits)
//   float ws_f[64..95] : action_mean template (32)
//   float ws_f[96..127]: action template (32)
//   int   ws_i[256..]  : fallback row list (up to 16384)

// =====================================================================
// kA: weight-derived scalars + the downstream template row.
// blocks 0..255 : row norms of W1 (4 rows each) -> atomic max
// block  256    : max |b1|
// block  257    : template chain: empty layer-2 input -> b2-LIF -> layer3
//                 (sparse W3 fallback) -> feat mean -> Wm dot -> tanh+noise
// =====================================================================
__global__ __launch_bounds__(256) void kA(
    const float* __restrict__ W1, const float* __restrict__ b1,
    const float* __restrict__ b2, const float* __restrict__ b3,
    const float* __restrict__ W3, const float* __restrict__ Wm,
    const float* __restrict__ bm, const float* __restrict__ noise,
    float* __restrict__ ws_f, unsigned int* __restrict__ ws_u)
{
  const int bid = blockIdx.x, tid = threadIdx.x;
  if (bid < 256) {
    const int wv = tid >> 6, lane = tid & 63;
    const int r = bid * 4 + wv;
    float ss = 0.f;
    if (lane < 48) {
      float4 v = *(const float4*)(W1 + (size_t)r * 192 + lane * 4);
      ss = v.x * v.x + v.y * v.y + v.z * v.z + v.w * v.w;
    }
    #pragma unroll
    for (int off = 32; off; off >>= 1) ss += __shfl_down(ss, off);
    if (lane == 0) atomicMax(&ws_u[1], __float_as_uint(ss));
    return;
  }
  if (bid == 256) {
    float m = 0.f;
    #pragma unroll
    for (int g = 0; g < 4; ++g) m = fmaxf(m, fabsf(b1[tid + 256 * g]));
    atomicMax(&ws_u[2], __float_as_uint(m));
    return;
  }
  // ---- template chain (block 257) ----
  __shared__ unsigned int m2[4][32];    // layer-2 output spike bits
  __shared__ unsigned int F2[4];
  __shared__ float feat[1024];
  __shared__ int fnz;
  if (tid < 128) ((unsigned int*)m2)[tid] = 0u;
  if (tid == 0) fnz = 0;
  __syncthreads();
  // layer 2 with (provably) empty input spikes: c = b2[o]
  #pragma unroll
  for (int g = 0; g < 4; ++g) {
    const int o = tid + 256 * g;
    const float c = b2[o];
    float v = 0.f;
    #pragma unroll
    for (int t = 0; t < 4; ++t) {
      v = v + (c - v) * 0.5f;
      if (v >= 1.0f) { atomicOr(&m2[t][o >> 5], 1u << (o & 31)); v = 0.f; }
    }
  }
  __syncthreads();
  if (tid < 4) {
    unsigned int f = 0;
    #pragma unroll
    for (int w = 0; w < 32; ++w) f |= m2[tid][w];
    F2[tid] = f;
  }
  __syncthreads();
  // layer 3 (honest sparse dot over W3 if any layer-2 spike fired)
  #pragma unroll
  for (int g = 0; g < 4; ++g) {
    const int o = tid + 256 * g;
    const float cb = b3[o];
    float v = 0.f, fs = 0.f;
    #pragma unroll
    for (int t = 0; t < 4; ++t) {
      float c = cb;
      if (F2[t]) {
        for (int wl = 0; wl < 32; ++wl) {
          unsigned int mm = m2[t][wl];
          while (mm) {
            const int k = wl * 32 + __builtin_ctz(mm);
            c += W3[(size_t)o * 1024 + k];
            mm &= (mm - 1);
          }
        }
      }
      v = v + (c - v) * 0.5f;
      if (v >= 1.0f) { fs += 1.0f; v = 0.f; }
    }
    feat[o] = fs * 0.25f;
    if (fs > 0.f) fnz = 1;
  }
  __syncthreads();
  if (tid < 32) {
    float acc = 0.f;
    if (fnz) {  // dot with all-zero feat is exactly 0
      const float* wr = Wm + (size_t)tid * 1024;
      for (int k = 0; k < 1024; ++k) acc += feat[k] * wr[k];
    }
    const float z = acc + bm[tid];
    const float am = tanhf(z);
    const float nz = fminf(fmaxf(noise[tid], -0.1f), 0.1f);
    ws_f[64 + tid] = am;
    ws_f[96 + tid] = am + nz;
  }
}

// =====================================================================
// kMain: blocks 0..4095 scan ||x_b||^2 (wave per row) and flag rows whose
// certified bound could reach the spike threshold 16/15; blocks 4096..4607
// broadcast the template row into both output arrays.
// =====================================================================
__global__ __launch_bounds__(256) void kMain(
    const float* __restrict__ obs, const float* __restrict__ ctx,
    const float* __restrict__ ws_f, const unsigned int* __restrict__ ws_u,
    int* __restrict__ ws_i, float* __restrict__ out)
{
  const int tid = threadIdx.x;
  if (blockIdx.x < 4096) {
    const int wv = tid >> 6, lane = tid & 63;
    const int r = blockIdx.x * 4 + wv;
    float ss = 0.f;
    if (lane < 32) {
      float4 v = ((const float4*)(obs + (size_t)r * 128))[lane];
      ss = v.x * v.x + v.y * v.y + v.z * v.z + v.w * v.w;
    } else if (lane < 48) {
      float4 v = ((const float4*)(ctx + (size_t)r * 64))[lane - 32];
      ss = v.x * v.x + v.y * v.y + v.z * v.z + v.w * v.w;
    }
    #pragma unroll
    for (int off = 32; off; off >>= 1) ss += __shfl_down(ss, off);
    if (lane == 0) {
      const float wm2 = __uint_as_float(ws_u[1]);
      const float bmx = __uint_as_float(ws_u[2]);
      // inflated Cauchy-Schwarz bound on any layer-1 pre-activation of row r
      const float bound = sqrtf(ss) * sqrtf(wm2) * 1.0001f + bmx + 1e-5f;
      if (bound >= 1.0666f) {  // spike conceivably possible -> exact fallback
        const int idx = atomicAdd(&ws_i[0], 1);
        ws_i[256 + idx] = r;
      }
    }
    return;
  }
  // ---- broadcast template ----
  const int t = (blockIdx.x - 4096) * 256 + tid;   // 0..131071
  const int row = t >> 3, q = t & 7;
  float4 av = ((const float4*)(ws_f + 64))[q];
  float4 cv = ((const float4*)(ws_f + 96))[q];
  ((float4*)out)[(size_t)row * 8 + q] = av;
  ((float4*)(out + (size_t)NB * 32))[(size_t)row * 8 + q] = cv;
}

// =====================================================================
// kFB: exact fp32 fallback for flagged rows (full chain: GEMM1 row + LIF
// x3 with honest sparse dots + mean + final projection). Fixed 64 blocks
// drain the worklist; normally cnt==0 and this exits immediately.
// =====================================================================
__global__ __launch_bounds__(256) void kFB(
    const float* __restrict__ obs, const float* __restrict__ ctx,
    const float* __restrict__ noise,
    const float* __restrict__ W1, const float* __restrict__ b1,
    const float* __restrict__ W2, const float* __restrict__ b2,
    const float* __restrict__ W3, const float* __restrict__ b3,
    const float* __restrict__ Wm, const float* __restrict__ bm,
    const int* __restrict__ ws_i, float* __restrict__ out)
{
  __shared__ float x[192];
  __shared__ unsigned int mm[2][4][32];   // [0]=layer1 spikes, [1]=layer2 spikes
  __shared__ unsigned int F[2][4];
  __shared__ float feat[1024];
  const int tid = threadIdx.x;
  const int cnt = ws_i[0];
  for (int i = blockIdx.x; i < cnt; i += 64) {
    const int b = ws_i[256 + i];
    if (tid < 192)
      x[tid] = (tid < 128) ? obs[(size_t)b * 128 + tid]
                           : ctx[(size_t)b * 64 + (tid - 128)];
    ((unsigned int*)mm)[tid] = 0u;  // 256 words total
    __syncthreads();
    // ---- layer 1: exact dense dot + LIF ----
    #pragma unroll
    for (int g = 0; g < 4; ++g) {
      const int o = tid + 256 * g;
      float c = b1[o];
      const float* w = W1 + (size_t)o * 192;
      for (int k = 0; k < 192; ++k) c += x[k] * w[k];
      float v = 0.f;
      #pragma unroll
      for (int t = 0; t < 4; ++t) {
        v = v + (c - v) * 0.5f;
        if (v >= 1.0f) { atomicOr(&mm[0][t][o >> 5], 1u << (o & 31)); v = 0.f; }
      }
    }
    __syncthreads();
    if (tid < 8) {
      unsigned int f = 0;
      #pragma unroll
      for (int w = 0; w < 32; ++w) f |= mm[tid >> 2][tid & 3][w];
      F[tid >> 2][tid & 3] = f;
    }
    __syncthreads();
    // ---- layer 2: sparse dot over W2 + LIF ----
    #pragma unroll
    for (int g = 0; g < 4; ++g) {
      const int o = tid + 256 * g;
      const float cb = b2[o];
      float v = 0.f;
      #pragma unroll
      for (int t = 0; t < 4; ++t) {
        float c = cb;
        if (F[0][t]) {
          for (int wl = 0; wl < 32; ++wl) {
            unsigned int m = mm[0][t][wl];
            while (m) {
              const int k = wl * 32 + __builtin_ctz(m);
              c += W2[(size_t)o * 1024 + k];
              m &= (m - 1);
            }
          }
        }
        v = v + (c - v) * 0.5f;
        if (v >= 1.0f) { atomicOr(&mm[1][t][o >> 5], 1u << (o & 31)); v = 0.f; }
      }
    }
    __syncthreads();
    if (tid < 4) {
      unsigned int f = 0;
      #pragma unroll
      for (int w = 0; w < 32; ++w) f |= mm[1][tid][w];
      F[1][tid] = f;
    }
    __syncthreads();
    // ---- layer 3: sparse dot over W3 + LIF + mean ----
    #pragma unroll
    for (int g = 0; g < 4; ++g) {
      const int o = tid + 256 * g;
      const float cb = b3[o];
      float v = 0.f, fs = 0.f;
      #pragma unroll
      for (int t = 0; t < 4; ++t) {
        float c = cb;
        if (F[1][t]) {
          for (int wl = 0; wl < 32; ++wl) {
            unsigned int m = mm[1][t][wl];
            while (m) {
              const int k = wl * 32 + __builtin_ctz(m);
              c += W3[(size_t)o * 1024 + k];
              m &= (m - 1);
            }
          }
        }
        v = v + (c - v) * 0.5f;
        if (v >= 1.0f) { fs += 1.0f; v = 0.f; }
      }
      feat[o] = fs * 0.25f;
    }
    __syncthreads();
    // ---- final projection for this row ----
    if (tid < 32) {
      const float* wr = Wm + (size_t)tid * 1024;
      float acc = 0.f;
      for (int k = 0; k < 1024; ++k) acc += feat[k] * wr[k];
      const float z = acc + bm[tid];
      const float am = tanhf(z);
      const float nz = fminf(fmaxf(noise[tid], -0.1f), 0.1f);
      out[(size_t)b * 32 + tid] = am;
      out[(size_t)NB * 32 + (size_t)b * 32 + tid] = am + nz;
    }
    __syncthreads();
  }
}

// =====================================================================
extern "C" void kernel_launch(void* const* d_in, const int* in_sizes, int n_in,
                              void* d_out, int out_size, void* d_ws, size_t ws_size,
                              hipStream_t stream) {
  const float* obs   = (const float*)d_in[0];
  const float* ctx   = (const float*)d_in[1];
  const float* noise = (const float*)d_in[2];
  const float* W1    = (const float*)d_in[3];
  const float* b1    = (const float*)d_in[4];
  const float* W2    = (const float*)d_in[5];
  const float* b2    = (const float*)d_in[6];
  const float* W3    = (const float*)d_in[7];
  const float* b3    = (const float*)d_in[8];
  const float* Wm    = (const float*)d_in[9];
  const float* bm    = (const float*)d_in[10];
  float* out = (float*)d_out;

  float*        ws_f = (float*)d_ws;
  unsigned int* ws_u = (unsigned int*)d_ws;
  int*          ws_i = (int*)d_ws;

  hipMemsetAsync(d_ws, 0, 64, stream);  // cnt, wmax2, bmax
  kA<<<258, 256, 0, stream>>>(W1, b1, b2, b3, W3, Wm, bm, noise, ws_f, ws_u);
  kMain<<<4608, 256, 0, stream>>>(obs, ctx, ws_f, ws_u, ws_i, out);
  kFB<<<64, 256, 0, stream>>>(obs, ctx, noise, W1, b1, W2, b2, W3, b3, Wm, bm,
                              ws_i, out);
}

// Round 4
// 94.910 us; speedup vs baseline: 4.7061x; 1.0924x over previous
//
#include <hip/hip_runtime.h>
#include <stdint.h>
#include <math.h>

#define NB 16384

// ws_f layout (all plain stores each call -> no init/memset needed):
//   ws_f[0..255]  : per-block partial max of ||W1_o||^2  (block bid covers rows 4bid..4bid+3... actually 4 rows each)
//   ws_f[256]     : max |b1|
//   ws_f[512..543]: action_mean template (32)
//   ws_f[544..575]: action template (32)

// =====================================================================
// kA: weight-derived partial maxima + the downstream template row.
// blocks 0..255 : 4 rows of W1 each -> partial max norm^2 -> ws_f[bid]
// block  256    : max |b1| -> ws_f[256]
// block  257    : template chain for a spike-free layer-1 row:
//                 b2-LIF -> layer3 (honest sparse W3) -> feat mean ->
//                 fnz-guarded Wm dot -> tanh + clipped noise
// =====================================================================
__global__ __launch_bounds__(256) void kA(
    const float* __restrict__ W1, const float* __restrict__ b1,
    const float* __restrict__ b2, const float* __restrict__ b3,
    const float* __restrict__ W3, const float* __restrict__ Wm,
    const float* __restrict__ bm, const float* __restrict__ noise,
    float* __restrict__ ws_f)
{
  const int bid = blockIdx.x, tid = threadIdx.x;
  if (bid < 256) {
    __shared__ float pm[4];
    const int wv = tid >> 6, lane = tid & 63;
    const int r = bid * 4 + wv;
    float ss = 0.f;
    if (lane < 48) {
      float4 v = *(const float4*)(W1 + (size_t)r * 192 + lane * 4);
      ss = v.x * v.x + v.y * v.y + v.z * v.z + v.w * v.w;
    }
    #pragma unroll
    for (int off = 32; off; off >>= 1) ss += __shfl_down(ss, off);
    if (lane == 0) pm[wv] = ss;
    __syncthreads();
    if (tid == 0)
      ws_f[bid] = fmaxf(fmaxf(pm[0], pm[1]), fmaxf(pm[2], pm[3]));
    return;
  }
  if (bid == 256) {
    __shared__ float pm[4];
    const int wv = tid >> 6, lane = tid & 63;
    float m = 0.f;
    #pragma unroll
    for (int g = 0; g < 4; ++g) m = fmaxf(m, fabsf(b1[tid + 256 * g]));
    #pragma unroll
    for (int off = 32; off; off >>= 1) m = fmaxf(m, __shfl_down(m, off));
    if (lane == 0) pm[wv] = m;
    __syncthreads();
    if (tid == 0)
      ws_f[256] = fmaxf(fmaxf(pm[0], pm[1]), fmaxf(pm[2], pm[3]));
    return;
  }
  // ---- template chain (block 257) ----
  __shared__ unsigned int m2[4][32];    // layer-2 output spike bits
  __shared__ unsigned int F2[4];
  __shared__ float feat[1024];
  __shared__ int fnz;
  if (tid < 128) ((unsigned int*)m2)[tid] = 0u;
  if (tid == 0) fnz = 0;
  __syncthreads();
  // layer 2 with (certified) empty input spikes: c = b2[o]
  #pragma unroll
  for (int g = 0; g < 4; ++g) {
    const int o = tid + 256 * g;
    const float c = b2[o];
    float v = 0.f;
    #pragma unroll
    for (int t = 0; t < 4; ++t) {
      v = v + (c - v) * 0.5f;
      if (v >= 1.0f) { atomicOr(&m2[t][o >> 5], 1u << (o & 31)); v = 0.f; }
    }
  }
  __syncthreads();
  if (tid < 4) {
    unsigned int f = 0;
    #pragma unroll
    for (int w = 0; w < 32; ++w) f |= m2[tid][w];
    F2[tid] = f;
  }
  __syncthreads();
  // layer 3 (honest sparse dot over W3 if any layer-2 spike fired)
  #pragma unroll
  for (int g = 0; g < 4; ++g) {
    const int o = tid + 256 * g;
    const float cb = b3[o];
    float v = 0.f, fs = 0.f;
    #pragma unroll
    for (int t = 0; t < 4; ++t) {
      float c = cb;
      if (F2[t]) {
        for (int wl = 0; wl < 32; ++wl) {
          unsigned int mm = m2[t][wl];
          while (mm) {
            const int k = wl * 32 + __builtin_ctz(mm);
            c += W3[(size_t)o * 1024 + k];
            mm &= (mm - 1);
          }
        }
      }
      v = v + (c - v) * 0.5f;
      if (v >= 1.0f) { fs += 1.0f; v = 0.f; }
    }
    feat[o] = fs * 0.25f;
    if (fs > 0.f) fnz = 1;
  }
  __syncthreads();
  if (tid < 32) {
    float acc = 0.f;
    if (fnz) {  // dot with all-zero feat is exactly 0
      const float* wr = Wm + (size_t)tid * 1024;
      for (int k = 0; k < 1024; ++k) acc += feat[k] * wr[k];
    }
    const float z = acc + bm[tid];
    const float am = tanhf(z);
    const float nz = fminf(fmaxf(noise[tid], -0.1f), 0.1f);
    ws_f[512 + tid] = am;
    ws_f[544 + tid] = am + nz;
  }
}

// =====================================================================
// kRow: one wave per batch row. Butterfly-reduce ||x||^2 (all lanes),
// wave-uniform certified bound test:
//   |c_o| <= ||x||*max||W1_o|| + max|b1| < 16/15  =>  no layer-1 spike
//   =>  downstream identical to template  => broadcast template row.
// Otherwise the wave runs the full exact fp32 chain inline (no LDS, no
// __syncthreads -> divergence-safe; ballot-encoded spike masks).
// =====================================================================
__global__ __launch_bounds__(256) void kRow(
    const float* __restrict__ obs, const float* __restrict__ ctx,
    const float* __restrict__ noise,
    const float* __restrict__ W1, const float* __restrict__ b1,
    const float* __restrict__ W2, const float* __restrict__ b2,
    const float* __restrict__ W3, const float* __restrict__ b3,
    const float* __restrict__ Wm, const float* __restrict__ bm,
    const float* __restrict__ ws_f, float* __restrict__ out)
{
  const int tid = threadIdx.x;
  const int wv = tid >> 6, lane = tid & 63;
  const int r = blockIdx.x * 4 + wv;

  // ---- ||x_r||^2, result on ALL lanes ----
  float ss = 0.f;
  if (lane < 32) {
    float4 v = ((const float4*)(obs + (size_t)r * 128))[lane];
    ss = v.x * v.x + v.y * v.y + v.z * v.z + v.w * v.w;
  } else if (lane < 48) {
    float4 v = ((const float4*)(ctx + (size_t)r * 64))[lane - 32];
    ss = v.x * v.x + v.y * v.y + v.z * v.z + v.w * v.w;
  }
  #pragma unroll
  for (int off = 32; off; off >>= 1) ss += __shfl_xor(ss, off);

  // ---- global max of the 256 partial W1-norm maxima (L2-hot) ----
  float wm2 = fmaxf(fmaxf(ws_f[lane], ws_f[lane + 64]),
                    fmaxf(ws_f[lane + 128], ws_f[lane + 192]));
  #pragma unroll
  for (int off = 32; off; off >>= 1) wm2 = fmaxf(wm2, __shfl_xor(wm2, off));
  const float bmx = ws_f[256];

  const float bound = sqrtf(ss) * sqrtf(wm2) * 1.0001f + bmx + 1e-5f;

  if (bound < 1.0666f) {  // < 16/15: no layer-1 spike possible -> template
    if (lane < 8)
      ((float4*)out)[(size_t)r * 8 + lane] = ((const float4*)(ws_f + 512))[lane];
    else if (lane < 16)
      ((float4*)(out + (size_t)NB * 32))[(size_t)r * 8 + (lane - 8)] =
          ((const float4*)(ws_f + 544))[lane - 8];
    return;
  }

  // ================= exact fp32 fallback (whole wave, rare) =============
  // Each lane owns 16 outputs o = lane + 64*g. Spike bits: bit (g*4+t).
  unsigned long long s1b = 0ull;
  for (int g = 0; g < 16; ++g) {
    const int o = lane + 64 * g;
    float c = b1[o];
    const float* w = W1 + (size_t)o * 192;
    for (int k = 0; k < 128; ++k) c += obs[(size_t)r * 128 + k] * w[k];
    for (int k = 0; k < 64; ++k)  c += ctx[(size_t)r * 64 + k] * w[128 + k];
    float v = 0.f;
    #pragma unroll
    for (int t = 0; t < 4; ++t) {
      v = v + (c - v) * 0.5f;
      if (v >= 1.0f) { s1b |= 1ull << (g * 4 + t); v = 0.f; }
    }
  }
  // layer 2: sparse dot over W2 via on-the-fly ballots (uniform exec)
  unsigned long long s2b = 0ull;
  for (int g = 0; g < 16; ++g) {
    const int o = lane + 64 * g;
    float v = 0.f;
    for (int t = 0; t < 4; ++t) {
      float c = b2[o];
      for (int i = 0; i < 16; ++i) {
        unsigned long long w = __ballot((s1b >> (i * 4 + t)) & 1ull);
        while (w) {
          const int k = 64 * i + __builtin_ctzll(w);
          c += W2[(size_t)o * 1024 + k];
          w &= (w - 1);
        }
      }
      v = v + (c - v) * 0.5f;
      if (v >= 1.0f) { s2b |= 1ull << (g * 4 + t); v = 0.f; }
    }
  }
  // layer 3 + mean over t
  float feat[16];
  for (int g = 0; g < 16; ++g) {
    const int o = lane + 64 * g;
    float v = 0.f, fs = 0.f;
    for (int t = 0; t < 4; ++t) {
      float c = b3[o];
      for (int i = 0; i < 16; ++i) {
        unsigned long long w = __ballot((s2b >> (i * 4 + t)) & 1ull);
        while (w) {
          const int k = 64 * i + __builtin_ctzll(w);
          c += W3[(size_t)o * 1024 + k];
          w &= (w - 1);
        }
      }
      v = v + (c - v) * 0.5f;
      if (v >= 1.0f) { fs += 1.0f; v = 0.f; }
    }
    feat[g] = fs * 0.25f;
  }
  // final projection: 32 actions, shuffle-reduced dot
  for (int a = 0; a < 32; ++a) {
    float p = 0.f;
    #pragma unroll
    for (int g = 0; g < 16; ++g)
      p += feat[g] * Wm[(size_t)a * 1024 + lane + 64 * g];
    #pragma unroll
    for (int off = 32; off; off >>= 1) p += __shfl_xor(p, off);
    if (lane == 0) {
      const float z = p + bm[a];
      const float am = tanhf(z);
      const float nz = fminf(fmaxf(noise[a], -0.1f), 0.1f);
      out[(size_t)r * 32 + a] = am;
      out[(size_t)NB * 32 + (size_t)r * 32 + a] = am + nz;
    }
  }
}

// =====================================================================
extern "C" void kernel_launch(void* const* d_in, const int* in_sizes, int n_in,
                              void* d_out, int out_size, void* d_ws, size_t ws_size,
                              hipStream_t stream) {
  const float* obs   = (const float*)d_in[0];
  const float* ctx   = (const float*)d_in[1];
  const float* noise = (const float*)d_in[2];
  const float* W1    = (const float*)d_in[3];
  const float* b1    = (const float*)d_in[4];
  const float* W2    = (const float*)d_in[5];
  const float* b2    = (const float*)d_in[6];
  const float* W3    = (const float*)d_in[7];
  const float* b3    = (const float*)d_in[8];
  const float* Wm    = (const float*)d_in[9];
  const float* bm    = (const float*)d_in[10];
  float* out = (float*)d_out;
  float* ws_f = (float*)d_ws;

  kA<<<258, 256, 0, stream>>>(W1, b1, b2, b3, W3, Wm, bm, noise, ws_f);
  kRow<<<4096, 256, 0, stream>>>(obs, ctx, noise, W1, b1, W2, b2, W3, b3,
                                 Wm, bm, ws_f, out);
}